// Round 5
// baseline (574.337 us; speedup 1.0000x reference)
//
#include <hip/hip_runtime.h>
#include <hip/hip_bf16.h>

typedef __attribute__((ext_vector_type(8))) short bf16x8;
typedef __attribute__((ext_vector_type(4))) float f32x4;
typedef __attribute__((ext_vector_type(4))) unsigned short u16x4;
typedef __attribute__((ext_vector_type(8))) unsigned short u16x8;

#define SEQ   4096
#define DIM   1024
#define MTOT  16384
#define NT256 16            // SEQ/256 query tiles (256-granular packing)
#define NTRI2 136           // NT256*(NT256+1)/2 causal 256-tiles
#define TSZ2  65536         // elements per 256x256 tile
#define PSIZE2 ((size_t)NTRI2 * TSZ2)   // packed S elems per batch

static __device__ __forceinline__ unsigned short f2bf(float f) {
  union { float f; unsigned u; } v; v.f = f;
  unsigned r = v.u + 0x7FFFu + ((v.u >> 16) & 1u);
  return (unsigned short)(r >> 16);
}

static __device__ __forceinline__ unsigned short f2h(float f) {
  union { _Float16 h; unsigned short u; } v; v.h = (_Float16)f; return v.u;
}

static __device__ __forceinline__ float h2f(unsigned short u) {
  union { unsigned short u; _Float16 h; } v; v.u = u; return (float)v.h;
}

static __device__ __forceinline__ bf16x8 pack8(f32x4 a, f32x4 b) {
  bf16x8 v;
  v[0]=(short)f2bf(a[0]); v[1]=(short)f2bf(a[1]);
  v[2]=(short)f2bf(a[2]); v[3]=(short)f2bf(a[3]);
  v[4]=(short)f2bf(b[0]); v[5]=(short)f2bf(b[1]);
  v[6]=(short)f2bf(b[2]); v[7]=(short)f2bf(b[3]);
  return v;
}

// row index of lower-triangle tile id (id = ti*(ti+1)/2 + tj)
static __device__ __forceinline__ int tri_row(int id) {
  int ti = (int)((sqrtf(8.f * (float)id + 1.f) - 1.f) * 0.5f);
  while ((ti + 1) * (ti + 2) / 2 <= id) ++ti;
  while (ti * (ti + 1) / 2 > id) --ti;
  return ti;
}

// ---------------- fp32 -> bf16 preconvert ----------------
__global__ __launch_bounds__(256) void conv_bf16(
    const float* __restrict__ src, unsigned short* __restrict__ dst,
    int n8, float scale)
{
  const int i = blockIdx.x * 256 + threadIdx.x;
  if (i < n8) {
    const f32x4* s = (const f32x4*)(src + (size_t)i * 8);
    f32x4 a = s[0], b = s[1];
#pragma unroll
    for (int r = 0; r < 4; ++r) { a[r] *= scale; b[r] *= scale; }
    *(bf16x8*)(dst + (size_t)i * 8) = pack8(a, b);
  }
}

// all three weights in one launch; Wq gets 1/sqrt(D) folded in
__global__ __launch_bounds__(256) void conv_w3(
    const float* __restrict__ Wq, const float* __restrict__ Wk,
    const float* __restrict__ Wv, unsigned short* __restrict__ dst)
{
  const int i = blockIdx.x * 256 + threadIdx.x;
  const int seg = i >> 17;
  const int loc = i & 131071;
  const float* src = (seg == 0) ? Wq : (seg == 1) ? Wk : Wv;
  const float scale = (seg == 0) ? 0.03125f : 1.0f;
  const f32x4* s = (const f32x4*)(src + (size_t)loc * 8);
  f32x4 a = s[0], b = s[1];
#pragma unroll
  for (int r = 0; r < 4; ++r) { a[r] *= scale; b[r] *= scale; }
  *(bf16x8*)(dst + (size_t)i * 8) = pack8(a, b);
}

// ============================================================================
// 256x256 8-wave GEMM core, 4-phase/K-tile schedule (T3+T4+T2+T5).
// K-tile = 64, staged as 4 K-halves (kh): A-kh = 256 rows x 32 k = 16 KiB.
// LDS: As[2buf][2kh][256][32] + Bs same = 128 KiB.
// Swizzle: within a row (4 x 16B groups), group g holds global group
// g ^ ((row>>1)&3); applied on the GLOBAL source (global_load_lds writes
// linearly) and re-applied on ds_read -> 2-way banks (free).
// Phase p: vmcnt(8)+barrier -> issue 1 kh-stage (2 loads/thr) -> ds_read
// frags -> 16 MFMA (setprio-wrapped). Stage order: P1 A-kh1(T+1),
// P2 B-kh1(T+1), P3 A-kh0(T+2), P4 B-kh0(T+2); prologue A00,B00,A01,B01,
// A10,B10. Every read's source stage is exactly 8 loads old at its first
// read -> uniform vmcnt(8) is tight. Tail stages overrun into adjacent
// mapped ws regions and are never read.
// ============================================================================

static __device__ __forceinline__ void vm8_bar() {
  asm volatile("s_waitcnt vmcnt(8)" ::: "memory");
  __builtin_amdgcn_s_barrier();
  asm volatile("" ::: "memory");
}

// stage one K-half: 256 rows x 32 elems from gbase (row stride ld)
static __device__ __forceinline__ void stage_kh(
    const unsigned short* __restrict__ gbase, int ld,
    unsigned short* slot, int tid)
{
  const int w = tid >> 6, ln = tid & 63;
#pragma unroll
  for (int l = 0; l < 2; ++l) {
    const int row = (w * 2 + l) * 16 + (ln >> 2);
    const int e = (((ln & 3) ^ ((row >> 1) & 3)) * 8);
    __builtin_amdgcn_global_load_lds(
        (const __attribute__((address_space(1))) void*)(gbase + (size_t)row * ld + e),
        (__attribute__((address_space(3))) void*)&slot[(w * 2 + l) * 512], 16, 0, 0);
  }
}

// phase with B-frag read: 4 A + 4 B ds_read_b128, 16 MFMA (fm quarter fmQ=0)
static __device__ __forceinline__ void phase8(
    const unsigned short* Akh, const unsigned short* Bkh, bf16x8 (&bq)[4],
    int wr, int wc, int l15, int quad, f32x4 (&acc)[8][4])
{
  bf16x8 af[4];
#pragma unroll
  for (int i = 0; i < 4; ++i) {
    const int ar = wr * 128 + i * 16 + l15;
    af[i] = *(const bf16x8*)&Akh[ar * 32 + ((quad ^ ((ar >> 1) & 3)) * 8)];
    const int br = wc * 64 + i * 16 + l15;
    bq[i] = *(const bf16x8*)&Bkh[br * 32 + ((quad ^ ((br >> 1) & 3)) * 8)];
  }
  __builtin_amdgcn_s_setprio(1);
#pragma unroll
  for (int i = 0; i < 4; ++i)
#pragma unroll
    for (int j = 0; j < 4; ++j)
      acc[i][j] = __builtin_amdgcn_mfma_f32_16x16x32_bf16(af[i], bq[j], acc[i][j], 0, 0, 0);
  __builtin_amdgcn_s_setprio(0);
}

// phase reusing bq registers: 4 A ds_read_b128, 16 MFMA (fm quarter 1)
static __device__ __forceinline__ void phase4(
    const unsigned short* Akh, const bf16x8 (&bq)[4],
    int wr, int l15, int quad, f32x4 (&acc)[8][4])
{
  bf16x8 af[4];
#pragma unroll
  for (int i = 0; i < 4; ++i) {
    const int ar = wr * 128 + (4 + i) * 16 + l15;
    af[i] = *(const bf16x8*)&Akh[ar * 32 + ((quad ^ ((ar >> 1) & 3)) * 8)];
  }
  __builtin_amdgcn_s_setprio(1);
#pragma unroll
  for (int i = 0; i < 4; ++i)
#pragma unroll
    for (int j = 0; j < 4; ++j)
      acc[4 + i][j] = __builtin_amdgcn_mfma_f32_16x16x32_bf16(af[i], bq[j], acc[4 + i][j], 0, 0, 0);
  __builtin_amdgcn_s_setprio(0);
}

// ---------------- QKV GEMM, z-fused, 8-phase: 256 blocks x 512 thr ----------
__global__ __launch_bounds__(512, 2) void qkv_gemm4(
    const unsigned short* __restrict__ xb,
    const unsigned short* __restrict__ Wb,
    unsigned short* __restrict__ outQ)
{
  __shared__ unsigned short As[2][2][256 * 32];
  __shared__ unsigned short Bs[2][2][256 * 32];

  const int bid = blockIdx.x;               // 256
  const int xcd = bid & 7, i = bid >> 3;
  const int mt = xcd * 8 + (i >> 2);        // A-panel locality per XCD
  const int nt = i & 3;
  const int m0 = mt * 256, n0 = nt * 256;

  const int tid = threadIdx.x;
  const int w = tid >> 6, ln = tid & 63;
  const int l15 = ln & 15, quad = ln >> 4;
  const int wr = w >> 2, wc = w & 3;

  const unsigned short* Abase = xb + (size_t)m0 * DIM;

  auto gA = [&](int v, int kh) { return Abase + (v & 15) * 64 + kh * 32; };
  auto gB = [&](int v, int kh) {
    return Wb + (size_t)(v >> 4) * (DIM * DIM) + (size_t)n0 * DIM + (v & 15) * 64 + kh * 32;
  };

  f32x4 acc[8][4] = {};

  stage_kh(gA(0, 0), DIM, As[0][0], tid);
  stage_kh(gB(0, 0), DIM, Bs[0][0], tid);
  stage_kh(gA(0, 1), DIM, As[0][1], tid);
  stage_kh(gB(0, 1), DIM, Bs[0][1], tid);
  stage_kh(gA(1, 0), DIM, As[1][0], tid);
  stage_kh(gB(1, 0), DIM, Bs[1][0], tid);

#pragma unroll 1
  for (int T = 0; T < 48; ++T) {
    const int b = T & 1;
    bf16x8 bq[4];
    vm8_bar();
    stage_kh(gA(T + 1, 1), DIM, As[b ^ 1][1], tid);
    phase8(As[b][0], Bs[b][0], bq, wr, wc, l15, quad, acc);
    vm8_bar();
    stage_kh(gB(T + 1, 1), DIM, Bs[b ^ 1][1], tid);
    phase4(As[b][0], bq, wr, l15, quad, acc);
    vm8_bar();
    stage_kh(gA(T + 2, 0), DIM, As[b][0], tid);
    phase8(As[b][1], Bs[b][1], bq, wr, wc, l15, quad, acc);
    vm8_bar();
    stage_kh(gB(T + 2, 0), DIM, Bs[b][0], tid);
    phase4(As[b][1], bq, wr, l15, quad, acc);

    if ((T & 15) == 15) {
      const int z = T >> 4;
      unsigned short* outb = outQ + (size_t)z * ((size_t)MTOT * DIM);
      if (z < 2) {
#pragma unroll
        for (int fm = 0; fm < 8; ++fm)
#pragma unroll
          for (int fn = 0; fn < 4; ++fn) {
            const int m = m0 + wr * 128 + fm * 16 + quad * 4;
            const int e = n0 + wc * 64 + fn * 16 + l15;
            unsigned short* pp = outb + (size_t)m * DIM + e;
#pragma unroll
            for (int r = 0; r < 4; ++r) pp[(size_t)r * DIM] = f2bf(acc[fm][fn][r]);
          }
      } else {
#pragma unroll
        for (int fm = 0; fm < 8; ++fm)
#pragma unroll
          for (int fn = 0; fn < 4; ++fn) {
            const int m = m0 + wr * 128 + fm * 16 + quad * 4;   // s index
            const int e = n0 + wc * 64 + fn * 16 + l15;         // dim index
            const int bb = m >> 12, ss = m & 4095;
            u16x4 v4;
#pragma unroll
            for (int r = 0; r < 4; ++r) v4[r] = f2bf(acc[fm][fn][r]);
            *(u16x4*)(outb + ((size_t)bb * DIM + e) * SEQ + ss) = v4;
          }
      }
#pragma unroll
      for (int fm = 0; fm < 8; ++fm)
#pragma unroll
        for (int fn = 0; fn < 4; ++fn) acc[fm][fn] = (f32x4){0.f, 0.f, 0.f, 0.f};
    }
  }
}

// ---------------- S = Q K^T, 256-causal tiles, 8-phase, packed f16 ----------
// 272 blocks = 2 batches x 136 tri tiles, 16 K-tiles each.
__global__ __launch_bounds__(512, 2) void qk_gemm4(
    const unsigned short* __restrict__ Q,
    const unsigned short* __restrict__ K,
    unsigned short* __restrict__ Sp)
{
  __shared__ unsigned short As[2][2][256 * 32];
  __shared__ unsigned short Bs[2][2][256 * 32];

  const int bid = blockIdx.x;                       // 272 = 8 x 34
  const int item = (bid & 7) * 34 + (bid >> 3);
  const int bsel = item >= NTRI2;
  const int id = item - (bsel ? NTRI2 : 0);
  const int TI = tri_row(id);
  const int TJ = id - TI * (TI + 1) / 2;

  const unsigned short* Abase = Q + (size_t)bsel * SEQ * DIM + (size_t)(TI * 256) * DIM;
  const unsigned short* Bbase = K + (size_t)bsel * SEQ * DIM + (size_t)(TJ * 256) * DIM;

  const int tid = threadIdx.x;
  const int w = tid >> 6, ln = tid & 63;
  const int l15 = ln & 15, quad = ln >> 4;
  const int wr = w >> 2, wc = w & 3;

  auto gA = [&](int v, int kh) { return Abase + v * 64 + kh * 32; };
  auto gB = [&](int v, int kh) { return Bbase + v * 64 + kh * 32; };

  f32x4 acc[8][4] = {};

  stage_kh(gA(0, 0), DIM, As[0][0], tid);
  stage_kh(gB(0, 0), DIM, Bs[0][0], tid);
  stage_kh(gA(0, 1), DIM, As[0][1], tid);
  stage_kh(gB(0, 1), DIM, Bs[0][1], tid);
  stage_kh(gA(1, 0), DIM, As[1][0], tid);
  stage_kh(gB(1, 0), DIM, Bs[1][0], tid);

#pragma unroll 1
  for (int T = 0; T < 16; ++T) {
    const int b = T & 1;
    bf16x8 bq[4];
    vm8_bar();
    stage_kh(gA(T + 1, 1), DIM, As[b ^ 1][1], tid);
    phase8(As[b][0], Bs[b][0], bq, wr, wc, l15, quad, acc);
    vm8_bar();
    stage_kh(gB(T + 1, 1), DIM, Bs[b ^ 1][1], tid);
    phase4(As[b][0], bq, wr, l15, quad, acc);
    vm8_bar();
    stage_kh(gA(T + 2, 0), DIM, As[b][0], tid);
    phase8(As[b][1], Bs[b][1], bq, wr, wc, l15, quad, acc);
    vm8_bar();
    stage_kh(gB(T + 2, 0), DIM, Bs[b][0], tid);
    phase4(As[b][1], bq, wr, l15, quad, acc);
  }

  const int Lt = (TI + 1) << 8;
  unsigned short* base = Sp + (size_t)bsel * PSIZE2 + (size_t)(TI * (TI + 1) / 2) * TSZ2;
#pragma unroll
  for (int fm = 0; fm < 8; ++fm)
#pragma unroll
    for (int fn = 0; fn < 4; ++fn) {
      const int mloc = wr * 128 + fm * 16 + quad * 4;
      const int col  = TJ * 256 + wc * 64 + fn * 16 + l15;
      unsigned short* pp = base + (size_t)mloc * Lt + col;
#pragma unroll
      for (int r = 0; r < 4; ++r) pp[(size_t)r * Lt] = f2h(acc[fm][fn][r]);
    }
}

// ---------------- row softmax on 256-packed S: f16 in, bf16 out -------------
__global__ __launch_bounds__(256) void sm_rows_p(unsigned short* __restrict__ Sp)
{
  const int bid = blockIdx.x;
  const int bsel = bid >> 12;
  const int r = bid & 4095;
  const int TI = r >> 8, ri = r & 255;
  const int Lt = (TI + 1) << 8;
  const int len = r + 1;
  unsigned short* row = Sp + (size_t)bsel * PSIZE2 +
                        (size_t)(TI * (TI + 1) / 2) * TSZ2 + (size_t)ri * Lt;
  const int t = threadIdx.x;
  __shared__ float red[8];

  float v[16];
#pragma unroll
  for (int it = 0; it < 2; ++it) {
    const int c = t * 8 + it * 2048;
    if (c < Lt) {
      u16x8 h = *(const u16x8*)(row + c);
#pragma unroll
      for (int i = 0; i < 8; ++i)
        v[it * 8 + i] = (c + i < len) ? h2f(h[i]) : -1e30f;
    } else {
#pragma unroll
      for (int i = 0; i < 8; ++i) v[it * 8 + i] = -1e30f;
    }
  }

  float mx = v[0];
#pragma unroll
  for (int i = 1; i < 16; ++i) mx = fmaxf(mx, v[i]);
#pragma unroll
  for (int off = 1; off < 64; off <<= 1) mx = fmaxf(mx, __shfl_xor(mx, off));
  if ((t & 63) == 0) red[t >> 6] = mx;
  __syncthreads();
  mx = fmaxf(fmaxf(red[0], red[1]), fmaxf(red[2], red[3]));

  float p[16];
  float sm = 0.f;
#pragma unroll
  for (int it = 0; it < 2; ++it) {
    const int c = t * 8 + it * 2048;
#pragma unroll
    for (int i = 0; i < 8; ++i) {
      const int k = it * 8 + i;
      p[k] = (c + i < len) ? __expf(v[k] - mx) : 0.f;
      sm += p[k];
    }
  }
#pragma unroll
  for (int off = 1; off < 64; off <<= 1) sm += __shfl_xor(sm, off);
  if ((t & 63) == 0) red[4 + (t >> 6)] = sm;
  __syncthreads();
  const float inv = 1.f / (red[4] + red[5] + red[6] + red[7]);

#pragma unroll
  for (int it = 0; it < 2; ++it) {
    const int c = t * 8 + it * 2048;
    if (c < Lt) {
      u16x8 o;
#pragma unroll
      for (int i = 0; i < 8; ++i) o[i] = f2bf(p[it * 8 + i] * inv);
      *(u16x8*)(row + c) = o;
    }
  }
}

// ============================================================================
// 128x128-tile core (4 waves, BK=64, counted-vmcnt double buffer, swizzled)
// -- for PV. LDS 64 KiB -> 2 blocks/CU.
// ============================================================================
static __device__ __forceinline__ void head_sync(bool more) {
  if (more) asm volatile("s_waitcnt vmcnt(8)" ::: "memory");
  else      asm volatile("s_waitcnt vmcnt(0)" ::: "memory");
  __builtin_amdgcn_s_barrier();
  asm volatile("" ::: "memory");
}

static __device__ __forceinline__ void tail_sync() {
  asm volatile("" ::: "memory");
  __builtin_amdgcn_s_barrier();
  asm volatile("" ::: "memory");
}

static __device__ __forceinline__ void stage128(
    const unsigned short* __restrict__ Ab, int lda,
    const unsigned short* __restrict__ Bb, int ldb,
    unsigned short* Al, unsigned short* Bl, int tid)
{
  const int wv = tid >> 6, ln = tid & 63;
  const int lrow = ln >> 3, lcol = (ln & 7) * 8;
#pragma unroll
  for (int r = 0; r < 4; ++r) {
    const int row = (wv * 4 + r) * 8 + lrow;
    const int sw = ((row >> 2) & 3) << 4;
    __builtin_amdgcn_global_load_lds(
        (const __attribute__((address_space(1))) void*)(Ab + (size_t)row * lda + (lcol ^ sw)),
        (__attribute__((address_space(3))) void*)&Al[(wv * 4 + r) * 512], 16, 0, 0);
    __builtin_amdgcn_global_load_lds(
        (const __attribute__((address_space(1))) void*)(Bb + (size_t)row * ldb + (lcol ^ sw)),
        (__attribute__((address_space(3))) void*)&Bl[(wv * 4 + r) * 512], 16, 0, 0);
  }
}

static __device__ __forceinline__ void compute128(
    const unsigned short* Al, const unsigned short* Bl,
    int mw, int nw, int l15, int quad, f32x4 (&acc)[4][4])
{
  const int csw = (l15 >> 2) << 4;
#pragma unroll
  for (int ks = 0; ks < 2; ++ks) {
    bf16x8 af[4], bfr[4];
#pragma unroll
    for (int i = 0; i < 4; ++i) {
      af[i]  = *(const bf16x8*)&Al[(mw * 64 + i * 16 + l15) * 64 + ((ks * 32 + quad * 8) ^ csw)];
      bfr[i] = *(const bf16x8*)&Bl[(nw * 64 + i * 16 + l15) * 64 + ((ks * 32 + quad * 8) ^ csw)];
    }
    __builtin_amdgcn_s_setprio(1);
#pragma unroll
    for (int mi = 0; mi < 4; ++mi)
#pragma unroll
      for (int ni = 0; ni < 4; ++ni)
        acc[mi][ni] = __builtin_amdgcn_mfma_f32_16x16x32_bf16(af[mi], bfr[ni], acc[mi][ni], 0, 0, 0);
    __builtin_amdgcn_s_setprio(0);
  }
}

static __device__ __forceinline__ void gemm128_pipe(
    const unsigned short* __restrict__ Ab, int lda,
    const unsigned short* __restrict__ Bb, int ldb, int nt,
    unsigned short (*Al)[128 * 64], unsigned short (*Bl)[128 * 64],
    int tid, int mw, int nw, int l15, int quad, f32x4 (&acc)[4][4])
{
  stage128(Ab, lda, Bb, ldb, Al[0], Bl[0], tid);
  if (nt > 1) stage128(Ab + 64, lda, Bb + 64, ldb, Al[1], Bl[1], tid);
#pragma unroll 1
  for (int v = 0; v < nt; ++v) {
    const int p = v & 1;
    head_sync(v + 1 < nt);
    compute128(Al[p], Bl[p], mw, nw, l15, quad, acc);
    tail_sync();
    if (v + 2 < nt)
      stage128(Ab + (v + 2) * 64, lda, Bb + (v + 2) * 64, ldb, Al[p], Bl[p], tid);
  }
}

// ---------------- O = P * V on 256-packed S ---------------------------------
// 512 blocks = 2b x 8d x 32 ti(128-granular). Blocks j and j+256 have
// complementary ti -> round-robin dispatch pairs them per CU; 64 KiB LDS ->
// both resident.
__global__ __launch_bounds__(256) void pv_gemm_p(
    const unsigned short* __restrict__ Sp,
    const unsigned short* __restrict__ Vt,
    float* __restrict__ Ob)
{
  __shared__ unsigned short Al[2][128 * 64];
  __shared__ unsigned short Bl[2][128 * 64];

  const int bid = blockIdx.x;                 // 512
  const int d = bid & 7;
  const int rr_ = bid >> 3;                   // 0..63
  const int b = rr_ & 1;
  const int q = rr_ >> 1;                     // 0..31
  const int ti = (q & 16) ? (31 - (q & 15)) : q;

  const int TI = ti >> 1;
  const int Lt = (TI + 1) << 8;
  const int nt = (ti + 1) * 2;                // causal 64-k tiles

  const unsigned short* Sb = Sp + (size_t)b * PSIZE2 +
                             (size_t)(TI * (TI + 1) / 2) * TSZ2 +
                             (size_t)(ti & 1) * 128 * Lt;
  const unsigned short* Vb = Vt + (size_t)b * ((size_t)DIM * SEQ) +
                             (size_t)(d * 128) * SEQ;
  float* Outb = Ob + (size_t)b * ((size_t)SEQ * DIM);

  const int tid = threadIdx.x, ln = tid & 63, wv = tid >> 6;
  const int l15 = ln & 15, quad = ln >> 4;
  const int mw = wv >> 1, nw = wv & 1;

  f32x4 acc[4][4] = {};
  gemm128_pipe(Sb, Lt, Vb, SEQ, nt, Al, Bl, tid, mw, nw, l15, quad, acc);

#pragma unroll
  for (int mi = 0; mi < 4; ++mi)
#pragma unroll
    for (int ni = 0; ni < 4; ++ni) {
      const int m = ti * 128 + mw * 64 + mi * 16 + quad * 4;
      const int e = d * 128 + nw * 64 + ni * 16 + l15;
      float* pp = Outb + (size_t)m * DIM + e;
#pragma unroll
      for (int r = 0; r < 4; ++r) pp[(size_t)r * DIM] = acc[mi][ni][r];
    }
}

extern "C" void kernel_launch(void* const* d_in, const int* in_sizes, int n_in,
                              void* d_out, int out_size, void* d_ws, size_t ws_size,
                              hipStream_t stream) {
  const float* x  = (const float*)d_in[0];
  const float* Wq = (const float*)d_in[1];
  const float* Wk = (const float*)d_in[2];
  const float* Wv = (const float*)d_in[3];
  float* out = (float*)d_out;

  // ws layout (134.25 MB):
  //   [0,38MB):    xb (bf16 x, 32MB) + Wb (bf16 weights, 6MB)
  //                -> after qkv: 256-packed causal S, 2 batches (2 x 17.8MB)
  //   [38,70MB):   Q bf16   [70,102MB): K bf16   [102,134MB): Vt bf16
  char* wsb = (char*)d_ws;
  unsigned short* xb = (unsigned short*)wsb;
  unsigned short* Wb = (unsigned short*)(wsb + (32u << 20));
  unsigned short* Qb = (unsigned short*)(wsb + (38u << 20));
  unsigned short* Sp = xb;

  conv_bf16<<<8192, 256, 0, stream>>>(x, xb, 2097152, 1.0f);
  conv_w3<<<1536, 256, 0, stream>>>(Wq, Wk, Wv, Wb);

  qkv_gemm4<<<256, 512, 0, stream>>>(xb, Wb, Qb);

  const size_t n = (size_t)MTOT * DIM;
  for (int p = 0; p < 2; ++p) {
    const unsigned short* Qp  = Qb + (size_t)p * 2 * SEQ * DIM;
    const unsigned short* Kp  = Qb + n + (size_t)p * 2 * SEQ * DIM;
    const unsigned short* Vtp = Qb + 2 * n + (size_t)p * 2 * DIM * SEQ;
    float* Op = out + (size_t)p * 2 * SEQ * DIM;

    qk_gemm4<<<272, 512, 0, stream>>>(Qp, Kp, Sp);
    sm_rows_p<<<8192, 256, 0, stream>>>(Sp);
    pv_gemm_p<<<512, 256, 0, stream>>>(Sp, Vtp, Op);
  }
}

// Round 6
// 537.728 us; speedup vs baseline: 1.0681x; 1.0681x over previous
//
#include <hip/hip_runtime.h>
#include <hip/hip_bf16.h>

typedef __attribute__((ext_vector_type(8))) short bf16x8;
typedef __attribute__((ext_vector_type(4))) float f32x4;
typedef __attribute__((ext_vector_type(4))) unsigned short u16x4;
typedef __attribute__((ext_vector_type(8))) unsigned short u16x8;

#define SEQ   4096
#define DIM   1024
#define MTOT  16384
#define NTILE 32            // SEQ/128 query tiles (128-granular packing)
#define NTRI  528           // causal 128-tiles per batch
#define TSZ   16384         // elems per 128x128 tile
#define PSIZE ((size_t)NTRI * TSZ)

#define AS1 __attribute__((address_space(1)))
#define AS3 __attribute__((address_space(3)))

static __device__ __forceinline__ unsigned short f2bf(float f) {
  union { float f; unsigned u; } v; v.f = f;
  unsigned r = v.u + 0x7FFFu + ((v.u >> 16) & 1u);
  return (unsigned short)(r >> 16);
}

static __device__ __forceinline__ unsigned short f2h(float f) {
  union { _Float16 h; unsigned short u; } v; v.h = (_Float16)f; return v.u;
}

static __device__ __forceinline__ float h2f(unsigned short u) {
  union { unsigned short u; _Float16 h; } v; v.u = u; return (float)v.h;
}

static __device__ __forceinline__ bf16x8 pack8(f32x4 a, f32x4 b) {
  bf16x8 v;
  v[0]=(short)f2bf(a[0]); v[1]=(short)f2bf(a[1]);
  v[2]=(short)f2bf(a[2]); v[3]=(short)f2bf(a[3]);
  v[4]=(short)f2bf(b[0]); v[5]=(short)f2bf(b[1]);
  v[6]=(short)f2bf(b[2]); v[7]=(short)f2bf(b[3]);
  return v;
}

static __device__ __forceinline__ int tri_row(int id) {
  int ti = (int)((sqrtf(8.f * (float)id + 1.f) - 1.f) * 0.5f);
  while ((ti + 1) * (ti + 2) / 2 <= id) ++ti;
  while (ti * (ti + 1) / 2 > id) --ti;
  return ti;
}

// ---------------- fp32 -> bf16 preconvert ----------------
__global__ __launch_bounds__(256) void conv_bf16(
    const float* __restrict__ src, unsigned short* __restrict__ dst,
    int n8, float scale)
{
  const int i = blockIdx.x * 256 + threadIdx.x;
  if (i < n8) {
    const f32x4* s = (const f32x4*)(src + (size_t)i * 8);
    f32x4 a = s[0], b = s[1];
#pragma unroll
    for (int r = 0; r < 4; ++r) { a[r] *= scale; b[r] *= scale; }
    *(bf16x8*)(dst + (size_t)i * 8) = pack8(a, b);
  }
}

__global__ __launch_bounds__(256) void conv_w3(
    const float* __restrict__ Wq, const float* __restrict__ Wk,
    const float* __restrict__ Wv, unsigned short* __restrict__ dst)
{
  const int i = blockIdx.x * 256 + threadIdx.x;
  const int seg = i >> 17;
  const int loc = i & 131071;
  const float* src = (seg == 0) ? Wq : (seg == 1) ? Wk : Wv;
  const float scale = (seg == 0) ? 0.03125f : 1.0f;
  const f32x4* s = (const f32x4*)(src + (size_t)loc * 8);
  f32x4 a = s[0], b = s[1];
#pragma unroll
  for (int r = 0; r < 4; ++r) { a[r] *= scale; b[r] *= scale; }
  *(bf16x8*)(dst + (size_t)i * 8) = pack8(a, b);
}

// Counted-vmcnt head: buffer for tile v is valid once all but the 4 newest
// loads (= tile v+1's prefetch) have drained. Pipeline invariant: stage(v+2)
// is issued only after the tail barrier ending all reads of buf v (same slot).
static __device__ __forceinline__ void vm_head(bool more) {
  if (more) asm volatile("s_waitcnt vmcnt(4)" ::: "memory");
  else      asm volatile("s_waitcnt vmcnt(0)" ::: "memory");
  __builtin_amdgcn_s_barrier();
  asm volatile("" ::: "memory");
}

static __device__ __forceinline__ void tail_bar() {
  asm volatile("" ::: "memory");
  __builtin_amdgcn_s_barrier();
  asm volatile("" ::: "memory");
}

// ============================================================================
// QKV: 256x256 tile, 1024 thr / 16 waves (4x4), BK=64, 2 LDS buffers (128 KB).
// Wave (wr,wc) owns a 64x64 output -> acc[4][4] = 64 f32/lane -> <=128 regs
// -> 16 waves/CU (4/SIMD): ds_read latency and barrier skew hidden by TLP.
// LDS tile [256][64] (128B rows, 8 x 16B groups); group g holds global group
// g ^ (row&7) (pre-swizzled global source, same XOR on read -> 2-way banks).
// ============================================================================
static __device__ __forceinline__ void stage64(
    const unsigned short* __restrict__ g, int ld, unsigned short* dst, int tid)
{
  const int w = tid >> 6, ln = tid & 63;
#pragma unroll
  for (int l = 0; l < 2; ++l) {
    const int row = l * 128 + w * 8 + (ln >> 3);
    const int grp = (ln & 7) ^ (row & 7);
    __builtin_amdgcn_global_load_lds(
        (const AS1 void*)(g + (size_t)row * ld + grp * 8),
        (AS3 void*)&dst[(l * 128 + w * 8) * 64], 16, 0, 0);
  }
}

static __device__ __forceinline__ void compute64(
    const unsigned short* Au, const unsigned short* Bu,
    int wr, int wc, int l15, int quad, f32x4 (&acc)[4][4])
{
#pragma unroll
  for (int ks = 0; ks < 2; ++ks) {
    bf16x8 af[4], bq[4];
#pragma unroll
    for (int i = 0; i < 4; ++i) {
      const int ar = wr * 64 + i * 16 + l15;
      af[i] = *(const bf16x8*)&Au[ar * 64 + (((ks * 4 + quad) ^ (ar & 7)) * 8)];
      const int br = wc * 64 + i * 16 + l15;
      bq[i] = *(const bf16x8*)&Bu[br * 64 + (((ks * 4 + quad) ^ (br & 7)) * 8)];
    }
    __builtin_amdgcn_s_setprio(1);
#pragma unroll
    for (int i = 0; i < 4; ++i)
#pragma unroll
      for (int j = 0; j < 4; ++j)
        acc[i][j] = __builtin_amdgcn_mfma_f32_16x16x32_bf16(af[i], bq[j], acc[i][j], 0, 0, 0);
    __builtin_amdgcn_s_setprio(0);
  }
}

__global__ __launch_bounds__(1024, 4) void qkv_gemm5(
    const unsigned short* __restrict__ xb,
    const unsigned short* __restrict__ Wb,
    unsigned short* __restrict__ outQ)
{
  __shared__ unsigned short As[2][256 * 64];
  __shared__ unsigned short Bs[2][256 * 64];

  const int bid = blockIdx.x;               // 256
  const int xcd = bid & 7, i = bid >> 3;
  const int mt = xcd * 8 + (i >> 2);        // A-panel locality per XCD
  const int nt = i & 3;
  const int m0 = mt * 256, n0 = nt * 256;

  const int tid = threadIdx.x;
  const int w = tid >> 6, ln = tid & 63;
  const int l15 = ln & 15, quad = ln >> 4;
  const int wr = w >> 2, wc = w & 3;

  const unsigned short* Abase = xb + (size_t)m0 * DIM;
  auto gA = [&](int v) { return Abase + (v & 15) * 64; };
  auto gB = [&](int v) {
    return Wb + (size_t)(v >> 4) * (DIM * DIM) + (size_t)n0 * DIM + (v & 15) * 64;
  };

  f32x4 acc[4][4] = {};

  stage64(gA(0), DIM, As[0], tid);
  stage64(gB(0), DIM, Bs[0], tid);
  stage64(gA(1), DIM, As[1], tid);
  stage64(gB(1), DIM, Bs[1], tid);

#pragma unroll 1
  for (int v = 0; v < 48; ++v) {
    const int p = v & 1;
    vm_head(v + 1 < 48);
    compute64(As[p], Bs[p], wr, wc, l15, quad, acc);
    tail_bar();

    if ((v & 15) == 15) {                    // z boundary: epilogue BEFORE stage
      const int z = v >> 4;
      unsigned short* outb = outQ + (size_t)z * ((size_t)MTOT * DIM);
      if (z < 2) {
#pragma unroll
        for (int fm = 0; fm < 4; ++fm)
#pragma unroll
          for (int fn = 0; fn < 4; ++fn) {
            const int m = m0 + wr * 64 + fm * 16 + quad * 4;
            const int e = n0 + wc * 64 + fn * 16 + l15;
            unsigned short* pp = outb + (size_t)m * DIM + e;
#pragma unroll
            for (int r = 0; r < 4; ++r) pp[(size_t)r * DIM] = f2bf(acc[fm][fn][r]);
          }
      } else {
#pragma unroll
        for (int fm = 0; fm < 4; ++fm)
#pragma unroll
          for (int fn = 0; fn < 4; ++fn) {
            const int m = m0 + wr * 64 + fm * 16 + quad * 4;   // s index
            const int e = n0 + wc * 64 + fn * 16 + l15;        // dim index
            const int bb = m >> 12, ss = m & 4095;
            u16x4 v4;
#pragma unroll
            for (int r = 0; r < 4; ++r) v4[r] = f2bf(acc[fm][fn][r]);
            *(u16x4*)(outb + ((size_t)bb * DIM + e) * SEQ + ss) = v4;
          }
      }
#pragma unroll
      for (int fm = 0; fm < 4; ++fm)
#pragma unroll
        for (int fn = 0; fn < 4; ++fn) acc[fm][fn] = (f32x4){0.f, 0.f, 0.f, 0.f};
    }

    if (v + 2 < 48) {
      stage64(gA(v + 2), DIM, As[p], tid);
      stage64(gB(v + 2), DIM, Bs[p], tid);
    }
  }
}

// ============================================================================
// 128x128 tile, 256 thr / 4 waves, BK=32, 2 LDS buffers (32 KB -> 4 blocks/CU
// = 16 waves/CU). Same counted-vmcnt rhythm. LDS tile [128][32] (64B rows,
// 4 x 16B groups), group XOR (row>>1)&3 both sides -> 2-way banks.
// ============================================================================
static __device__ __forceinline__ void stage32(
    const unsigned short* __restrict__ g, int ld, unsigned short* dst, int tid)
{
  const int w = tid >> 6, ln = tid & 63;
#pragma unroll
  for (int l = 0; l < 2; ++l) {
    const int row = l * 64 + w * 16 + (ln >> 2);
    const int grp = (ln & 3) ^ ((row >> 1) & 3);
    __builtin_amdgcn_global_load_lds(
        (const AS1 void*)(g + (size_t)row * ld + grp * 8),
        (AS3 void*)&dst[(l * 64 + w * 16) * 32], 16, 0, 0);
  }
}

static __device__ __forceinline__ void compute32(
    const unsigned short* Al, const unsigned short* Bl,
    int mw, int nw, int l15, int quad, f32x4 (&acc)[4][4])
{
  bf16x8 af[4], bq[4];
#pragma unroll
  for (int i = 0; i < 4; ++i) {
    const int ar = mw * 64 + i * 16 + l15;
    af[i] = *(const bf16x8*)&Al[ar * 32 + ((quad ^ ((ar >> 1) & 3)) * 8)];
    const int br = nw * 64 + i * 16 + l15;
    bq[i] = *(const bf16x8*)&Bl[br * 32 + ((quad ^ ((br >> 1) & 3)) * 8)];
  }
  __builtin_amdgcn_s_setprio(1);
#pragma unroll
  for (int i = 0; i < 4; ++i)
#pragma unroll
    for (int j = 0; j < 4; ++j)
      acc[i][j] = __builtin_amdgcn_mfma_f32_16x16x32_bf16(af[i], bq[j], acc[i][j], 0, 0, 0);
  __builtin_amdgcn_s_setprio(0);
}

static __device__ __forceinline__ void gemm128_bk32(
    const unsigned short* __restrict__ Ab, int lda,
    const unsigned short* __restrict__ Bb, int ldb, int nt,
    unsigned short (*Al)[128 * 32], unsigned short (*Bl)[128 * 32],
    int tid, int mw, int nw, int l15, int quad, f32x4 (&acc)[4][4])
{
  stage32(Ab, lda, Bl ? Al[0] : Al[0], tid);   // keep call shape simple
  stage32(Bb, ldb, Bl[0], tid);
  stage32(Ab + 32, lda, Al[1], tid);
  stage32(Bb + 32, ldb, Bl[1], tid);
#pragma unroll 1
  for (int v = 0; v < nt; ++v) {
    const int p = v & 1;
    vm_head(v + 1 < nt);
    compute32(Al[p], Bl[p], mw, nw, l15, quad, acc);
    tail_bar();
    if (v + 2 < nt) {
      stage32(Ab + (v + 2) * 32, lda, Al[p], tid);
      stage32(Bb + (v + 2) * 32, ldb, Bl[p], tid);
    }
  }
}

// ---------------- S = Q K^T, 128-causal tiles, packed f16 -------------------
__global__ __launch_bounds__(256, 4) void qk_gemm5(
    const unsigned short* __restrict__ Q,
    const unsigned short* __restrict__ K,
    unsigned short* __restrict__ Sp)
{
  __shared__ unsigned short Al[2][128 * 32];
  __shared__ unsigned short Bl[2][128 * 32];

  const int bid = blockIdx.x;                 // 1056
  const int item = (bid & 7) * 132 + (bid >> 3);
  const int bsel = item >= NTRI;
  const int id = item - (bsel ? NTRI : 0);
  const int ti = tri_row(id);
  const int tj = id - ti * (ti + 1) / 2;

  const unsigned short* Qb = Q + (size_t)bsel * SEQ * DIM;
  const unsigned short* Kb = K + (size_t)bsel * SEQ * DIM;
  unsigned short* Sb = Sp + (size_t)bsel * PSIZE;

  const int tid = threadIdx.x, ln = tid & 63, wv = tid >> 6;
  const int l15 = ln & 15, quad = ln >> 4;
  const int mw = wv >> 1, nw = wv & 1;

  f32x4 acc[4][4] = {};
  gemm128_bk32(Qb + (size_t)(ti * 128) * DIM, DIM,
               Kb + (size_t)(tj * 128) * DIM, DIM, 32,
               Al, Bl, tid, mw, nw, l15, quad, acc);

  const int Lt = (ti + 1) << 7;
  unsigned short* base = Sb + (size_t)(ti * (ti + 1) / 2) * TSZ;
#pragma unroll
  for (int mi = 0; mi < 4; ++mi)
#pragma unroll
    for (int ni = 0; ni < 4; ++ni) {
      const int mloc = mw * 64 + mi * 16 + quad * 4;
      const int col  = tj * 128 + nw * 64 + ni * 16 + l15;
      unsigned short* p = base + (size_t)mloc * Lt + col;
#pragma unroll
      for (int r = 0; r < 4; ++r) p[(size_t)r * Lt] = f2h(acc[mi][ni][r]);
    }
}

// ---------------- row softmax on 128-packed S: f16 in, bf16 out -------------
__global__ __launch_bounds__(256) void sm_rows_p(unsigned short* __restrict__ Sp)
{
  const int bid = blockIdx.x;
  const int bsel = bid >> 12;
  const int r = bid & 4095;
  const int ti = r >> 7, ri = r & 127;
  const int Lt = (ti + 1) << 7;
  const int len = r + 1;
  unsigned short* row = Sp + (size_t)bsel * PSIZE +
                        (size_t)(ti * (ti + 1) / 2) * TSZ + (size_t)ri * Lt;
  const int t = threadIdx.x;
  __shared__ float red[8];

  float v[16];
#pragma unroll
  for (int it = 0; it < 2; ++it) {
    const int c = t * 8 + it * 2048;
    if (c < Lt) {
      u16x8 h = *(const u16x8*)(row + c);
#pragma unroll
      for (int i = 0; i < 8; ++i)
        v[it * 8 + i] = (c + i < len) ? h2f(h[i]) : -1e30f;
    } else {
#pragma unroll
      for (int i = 0; i < 8; ++i) v[it * 8 + i] = -1e30f;
    }
  }

  float mx = v[0];
#pragma unroll
  for (int i = 1; i < 16; ++i) mx = fmaxf(mx, v[i]);
#pragma unroll
  for (int off = 1; off < 64; off <<= 1) mx = fmaxf(mx, __shfl_xor(mx, off));
  if ((t & 63) == 0) red[t >> 6] = mx;
  __syncthreads();
  mx = fmaxf(fmaxf(red[0], red[1]), fmaxf(red[2], red[3]));

  float p[16];
  float sm = 0.f;
#pragma unroll
  for (int it = 0; it < 2; ++it) {
    const int c = t * 8 + it * 2048;
#pragma unroll
    for (int i = 0; i < 8; ++i) {
      const int k = it * 8 + i;
      p[k] = (c + i < len) ? __expf(v[k] - mx) : 0.f;
      sm += p[k];
    }
  }
#pragma unroll
  for (int off = 1; off < 64; off <<= 1) sm += __shfl_xor(sm, off);
  if ((t & 63) == 0) red[4 + (t >> 6)] = sm;
  __syncthreads();
  const float inv = 1.f / (red[4] + red[5] + red[6] + red[7]);

#pragma unroll
  for (int it = 0; it < 2; ++it) {
    const int c = t * 8 + it * 2048;
    if (c < Lt) {
      u16x8 o;
#pragma unroll
      for (int i = 0; i < 8; ++i) o[i] = f2bf(p[it * 8 + i] * inv);
      *(u16x8*)(row + c) = o;
    }
  }
}

// ---------------- O = P * V on 128-packed S ---------------------------------
// 512 blocks = 2b x 8d x 32 ti; blocks j and j+256 complementary ti.
// 32 KB LDS -> 4 blocks/CU.
__global__ __launch_bounds__(256, 4) void pv_gemm5(
    const unsigned short* __restrict__ Sp,
    const unsigned short* __restrict__ Vt,
    float* __restrict__ Ob)
{
  __shared__ unsigned short Al[2][128 * 32];
  __shared__ unsigned short Bl[2][128 * 32];

  const int bid = blockIdx.x;                 // 512
  const int d = bid & 7;
  const int rr_ = bid >> 3;                   // 0..63
  const int b = rr_ & 1;
  const int q = rr_ >> 1;                     // 0..31
  const int ti = (q & 16) ? (31 - (q & 15)) : q;
  const int Lt = (ti + 1) << 7;
  const int nt = (ti + 1) * 4;                // causal 32-k tiles

  const unsigned short* Sb = Sp + (size_t)b * PSIZE + (size_t)(ti * (ti + 1) / 2) * TSZ;
  const unsigned short* Vb = Vt + (size_t)b * ((size_t)DIM * SEQ) +
                             (size_t)(d * 128) * SEQ;
  float* Outb = Ob + (size_t)b * ((size_t)SEQ * DIM);

  const int tid = threadIdx.x, ln = tid & 63, wv = tid >> 6;
  const int l15 = ln & 15, quad = ln >> 4;
  const int mw = wv >> 1, nw = wv & 1;

  f32x4 acc[4][4] = {};
  gemm128_bk32(Sb, Lt, Vb, SEQ, nt, Al, Bl, tid, mw, nw, l15, quad, acc);

#pragma unroll
  for (int mi = 0; mi < 4; ++mi)
#pragma unroll
    for (int ni = 0; ni < 4; ++ni) {
      const int m = ti * 128 + mw * 64 + mi * 16 + quad * 4;
      const int e = d * 128 + nw * 64 + ni * 16 + l15;
      float* pp = Outb + (size_t)m * DIM + e;
#pragma unroll
      for (int r = 0; r < 4; ++r) pp[(size_t)r * DIM] = acc[mi][ni][r];
    }
}

extern "C" void kernel_launch(void* const* d_in, const int* in_sizes, int n_in,
                              void* d_out, int out_size, void* d_ws, size_t ws_size,
                              hipStream_t stream) {
  const float* x  = (const float*)d_in[0];
  const float* Wq = (const float*)d_in[1];
  const float* Wk = (const float*)d_in[2];
  const float* Wv = (const float*)d_in[3];
  float* out = (float*)d_out;

  // ws layout (134.25 MB):
  //   [0,38MB):    xb (bf16 x, 32MB) + Wb (bf16 weights, 6MB)
  //                -> after qkv: 128-packed causal S, 2 batches (2 x 16.5MB)
  //   [38,70MB):   Q bf16   [70,102MB): K bf16   [102,134MB): Vt bf16
  char* wsb = (char*)d_ws;
  unsigned short* xb = (unsigned short*)wsb;
  unsigned short* Wb = (unsigned short*)(wsb + (32u << 20));
  unsigned short* Qb = (unsigned short*)(wsb + (38u << 20));
  unsigned short* Sp = xb;

  conv_bf16<<<8192, 256, 0, stream>>>(x, xb, 2097152, 1.0f);
  conv_w3<<<1536, 256, 0, stream>>>(Wq, Wk, Wv, Wb);

  qkv_gemm5<<<256, 1024, 0, stream>>>(xb, Wb, Qb);

  const size_t n = (size_t)MTOT * DIM;
  for (int p = 0; p < 2; ++p) {
    const unsigned short* Qp  = Qb + (size_t)p * 2 * SEQ * DIM;
    const unsigned short* Kp  = Qb + n + (size_t)p * 2 * SEQ * DIM;
    const unsigned short* Vtp = Qb + 2 * n + (size_t)p * 2 * DIM * SEQ;
    float* Op = out + (size_t)p * 2 * SEQ * DIM;

    qk_gemm5<<<1056, 256, 0, stream>>>(Qp, Kp, Sp);
    sm_rows_p<<<8192, 256, 0, stream>>>(Sp);
    pv_gemm5<<<512, 256, 0, stream>>>(Sp, Vtp, Op);
  }
}

// Round 7
// 536.977 us; speedup vs baseline: 1.0696x; 1.0014x over previous
//
#include <hip/hip_runtime.h>
#include <hip/hip_bf16.h>

typedef __attribute__((ext_vector_type(8))) short bf16x8;
typedef __attribute__((ext_vector_type(4))) float f32x4;
typedef __attribute__((ext_vector_type(4))) unsigned short u16x4;
typedef __attribute__((ext_vector_type(8))) unsigned short u16x8;

#define SEQ   4096
#define DIM   1024
#define MTOT  16384
#define NT256 16
#define NTRI2 136
#define TSZ2  65536
#define PSIZE2 ((size_t)NTRI2 * TSZ2)

#define AS1 __attribute__((address_space(1)))
#define AS3 __attribute__((address_space(3)))

static __device__ __forceinline__ unsigned short f2bf(float f) {
  union { float f; unsigned u; } v; v.f = f;
  unsigned r = v.u + 0x7FFFu + ((v.u >> 16) & 1u);
  return (unsigned short)(r >> 16);
}

static __device__ __forceinline__ unsigned short f2h(float f) {
  union { _Float16 h; unsigned short u; } v; v.h = (_Float16)f; return v.u;
}

static __device__ __forceinline__ float h2f(unsigned short u) {
  union { unsigned short u; _Float16 h; } v; v.u = u; return (float)v.h;
}

static __device__ __forceinline__ bf16x8 pack8(f32x4 a, f32x4 b) {
  bf16x8 v;
  v[0]=(short)f2bf(a[0]); v[1]=(short)f2bf(a[1]);
  v[2]=(short)f2bf(a[2]); v[3]=(short)f2bf(a[3]);
  v[4]=(short)f2bf(b[0]); v[5]=(short)f2bf(b[1]);
  v[6]=(short)f2bf(b[2]); v[7]=(short)f2bf(b[3]);
  return v;
}

// ---------------- fp32 -> bf16 preconvert ----------------
__global__ __launch_bounds__(256) void conv_bf16(
    const float* __restrict__ src, unsigned short* __restrict__ dst,
    int n8, float scale)
{
  const int i = blockIdx.x * 256 + threadIdx.x;
  if (i < n8) {
    const f32x4* s = (const f32x4*)(src + (size_t)i * 8);
    f32x4 a = s[0], b = s[1];
#pragma unroll
    for (int r = 0; r < 4; ++r) { a[r] *= scale; b[r] *= scale; }
    *(bf16x8*)(dst + (size_t)i * 8) = pack8(a, b);
  }
}

__global__ __launch_bounds__(256) void conv_w3(
    const float* __restrict__ Wq, const float* __restrict__ Wk,
    const float* __restrict__ Wv, unsigned short* __restrict__ dst)
{
  const int i = blockIdx.x * 256 + threadIdx.x;
  const int seg = i >> 17;
  const int loc = i & 131071;
  const float* src = (seg == 0) ? Wq : (seg == 1) ? Wk : Wv;
  const float scale = (seg == 0) ? 0.03125f : 1.0f;
  const f32x4* s = (const f32x4*)(src + (size_t)loc * 8);
  f32x4 a = s[0], b = s[1];
#pragma unroll
  for (int r = 0; r < 4; ++r) { a[r] *= scale; b[r] *= scale; }
  *(bf16x8*)(dst + (size_t)i * 8) = pack8(a, b);
}

// ---------------- counted-vmcnt heads (N = next tile's loads/thread) --------
static __device__ __forceinline__ void head_n4(bool more) {
  if (more) asm volatile("s_waitcnt vmcnt(4)" ::: "memory");
  else      asm volatile("s_waitcnt vmcnt(0)" ::: "memory");
  __builtin_amdgcn_s_barrier();
  asm volatile("" ::: "memory");
}
static __device__ __forceinline__ void head_n3(bool more) {
  if (more) asm volatile("s_waitcnt vmcnt(3)" ::: "memory");
  else      asm volatile("s_waitcnt vmcnt(0)" ::: "memory");
  __builtin_amdgcn_s_barrier();
  asm volatile("" ::: "memory");
}
static __device__ __forceinline__ void head_n5(bool more) {
  if (more) asm volatile("s_waitcnt vmcnt(5)" ::: "memory");
  else      asm volatile("s_waitcnt vmcnt(0)" ::: "memory");
  __builtin_amdgcn_s_barrier();
  asm volatile("" ::: "memory");
}
static __device__ __forceinline__ void tail_bar() {
  asm volatile("" ::: "memory");
  __builtin_amdgcn_s_barrier();
  asm volatile("" ::: "memory");
}

// ============================================================================
// QKV: 256x256 tile, 1024 thr / 16 waves (4x4), BK=64 (r6, verified 135us).
// ============================================================================
static __device__ __forceinline__ void stage64(
    const unsigned short* __restrict__ g, int ld, unsigned short* dst, int tid)
{
  const int w = tid >> 6, ln = tid & 63;
#pragma unroll
  for (int l = 0; l < 2; ++l) {
    const int row = l * 128 + w * 8 + (ln >> 3);
    const int grp = (ln & 7) ^ (row & 7);
    __builtin_amdgcn_global_load_lds(
        (const AS1 void*)(g + (size_t)row * ld + grp * 8),
        (AS3 void*)&dst[(l * 128 + w * 8) * 64], 16, 0, 0);
  }
}

static __device__ __forceinline__ void compute64(
    const unsigned short* Au, const unsigned short* Bu,
    int wr, int wc, int l15, int quad, f32x4 (&acc)[4][4])
{
#pragma unroll
  for (int ks = 0; ks < 2; ++ks) {
    bf16x8 af[4], bq[4];
#pragma unroll
    for (int i = 0; i < 4; ++i) {
      const int ar = wr * 64 + i * 16 + l15;
      af[i] = *(const bf16x8*)&Au[ar * 64 + (((ks * 4 + quad) ^ (ar & 7)) * 8)];
      const int br = wc * 64 + i * 16 + l15;
      bq[i] = *(const bf16x8*)&Bu[br * 64 + (((ks * 4 + quad) ^ (br & 7)) * 8)];
    }
    __builtin_amdgcn_s_setprio(1);
#pragma unroll
    for (int i = 0; i < 4; ++i)
#pragma unroll
      for (int j = 0; j < 4; ++j)
        acc[i][j] = __builtin_amdgcn_mfma_f32_16x16x32_bf16(af[i], bq[j], acc[i][j], 0, 0, 0);
    __builtin_amdgcn_s_setprio(0);
  }
}

__global__ __launch_bounds__(1024, 4) void qkv_gemm5(
    const unsigned short* __restrict__ xb,
    const unsigned short* __restrict__ Wb,
    unsigned short* __restrict__ outQ)
{
  __shared__ unsigned short As[2][256 * 64];
  __shared__ unsigned short Bs[2][256 * 64];

  const int bid = blockIdx.x;               // 256
  const int xcd = bid & 7, i = bid >> 3;
  const int mt = xcd * 8 + (i >> 2);
  const int nt = i & 3;
  const int m0 = mt * 256, n0 = nt * 256;

  const int tid = threadIdx.x;
  const int w = tid >> 6, ln = tid & 63;
  const int l15 = ln & 15, quad = ln >> 4;
  const int wr = w >> 2, wc = w & 3;

  const unsigned short* Abase = xb + (size_t)m0 * DIM;
  auto gA = [&](int v) { return Abase + (v & 15) * 64; };
  auto gB = [&](int v) {
    return Wb + (size_t)(v >> 4) * (DIM * DIM) + (size_t)n0 * DIM + (v & 15) * 64;
  };

  f32x4 acc[4][4] = {};

  stage64(gA(0), DIM, As[0], tid);
  stage64(gB(0), DIM, Bs[0], tid);
  stage64(gA(1), DIM, As[1], tid);
  stage64(gB(1), DIM, Bs[1], tid);

#pragma unroll 1
  for (int v = 0; v < 48; ++v) {
    const int p = v & 1;
    head_n4(v + 1 < 48);
    compute64(As[p], Bs[p], wr, wc, l15, quad, acc);
    tail_bar();

    if ((v & 15) == 15) {
      const int z = v >> 4;
      unsigned short* outb = outQ + (size_t)z * ((size_t)MTOT * DIM);
      if (z < 2) {
#pragma unroll
        for (int fm = 0; fm < 4; ++fm)
#pragma unroll
          for (int fn = 0; fn < 4; ++fn) {
            const int m = m0 + wr * 64 + fm * 16 + quad * 4;
            const int e = n0 + wc * 64 + fn * 16 + l15;
            unsigned short* pp = outb + (size_t)m * DIM + e;
#pragma unroll
            for (int r = 0; r < 4; ++r) pp[(size_t)r * DIM] = f2bf(acc[fm][fn][r]);
          }
      } else {
#pragma unroll
        for (int fm = 0; fm < 4; ++fm)
#pragma unroll
          for (int fn = 0; fn < 4; ++fn) {
            const int m = m0 + wr * 64 + fm * 16 + quad * 4;
            const int e = n0 + wc * 64 + fn * 16 + l15;
            const int bb = m >> 12, ss = m & 4095;
            u16x4 v4;
#pragma unroll
            for (int r = 0; r < 4; ++r) v4[r] = f2bf(acc[fm][fn][r]);
            *(u16x4*)(outb + ((size_t)bb * DIM + e) * SEQ + ss) = v4;
          }
      }
#pragma unroll
      for (int fm = 0; fm < 4; ++fm)
#pragma unroll
        for (int fn = 0; fn < 4; ++fn) acc[fm][fn] = (f32x4){0.f, 0.f, 0.f, 0.f};
    }

    if (v + 2 < 48) {
      stage64(gA(v + 2), DIM, As[p], tid);
      stage64(gB(v + 2), DIM, Bs[p], tid);
    }
  }
}

// ============================================================================
// QK: 256m x 128n tile, BK=32, 512 thr / 8 waves (4m x 2n, wave 64x64).
// LDS 48 KB -> 2 blocks/CU (16 waves). 544 uniform blocks (2 batches).
// LDS rows 64B = 4 x 16B groups; slot s holds global group s ^ ((row>>1)&3).
// ============================================================================
static __device__ __forceinline__ void stageA_qk(
    const unsigned short* __restrict__ g, unsigned short* dst, int tid)
{
  const int w = tid >> 6, ln = tid & 63;
#pragma unroll
  for (int l = 0; l < 2; ++l) {
    const int row = l * 128 + w * 16 + (ln >> 2);
    const int grp = (ln & 3) ^ ((row >> 1) & 3);
    __builtin_amdgcn_global_load_lds(
        (const AS1 void*)(g + (size_t)row * DIM + grp * 8),
        (AS3 void*)&dst[(l * 128 + w * 16) * 32], 16, 0, 0);
  }
}

static __device__ __forceinline__ void stageB_qk(
    const unsigned short* __restrict__ g, unsigned short* dst, int tid)
{
  const int w = tid >> 6, ln = tid & 63;
  const int row = w * 16 + (ln >> 2);
  const int grp = (ln & 3) ^ ((row >> 1) & 3);
  __builtin_amdgcn_global_load_lds(
      (const AS1 void*)(g + (size_t)row * DIM + grp * 8),
      (AS3 void*)&dst[(w * 16) * 32], 16, 0, 0);
}

static __device__ __forceinline__ void compute_qk(
    const unsigned short* Al, const unsigned short* Bl,
    int wr, int wc, int l15, int quad, f32x4 (&acc)[4][4])
{
  bf16x8 af[4], bq[4];
#pragma unroll
  for (int i = 0; i < 4; ++i) {
    const int ar = wr * 64 + i * 16 + l15;
    af[i] = *(const bf16x8*)&Al[ar * 32 + ((quad ^ ((ar >> 1) & 3)) * 8)];
    const int br = wc * 64 + i * 16 + l15;
    bq[i] = *(const bf16x8*)&Bl[br * 32 + ((quad ^ ((br >> 1) & 3)) * 8)];
  }
  __builtin_amdgcn_s_setprio(1);
#pragma unroll
  for (int i = 0; i < 4; ++i)
#pragma unroll
    for (int j = 0; j < 4; ++j)
      acc[i][j] = __builtin_amdgcn_mfma_f32_16x16x32_bf16(af[i], bq[j], acc[i][j], 0, 0, 0);
  __builtin_amdgcn_s_setprio(0);
}

__global__ __launch_bounds__(512, 4) void qk_gemm6(
    const unsigned short* __restrict__ Q,
    const unsigned short* __restrict__ K,
    unsigned short* __restrict__ Sp)
{
  __shared__ unsigned short As[2][256 * 32];
  __shared__ unsigned short Bs[2][128 * 32];

  const int bid = blockIdx.x;                 // 544 = 8 x 68
  const int item = (bid & 7) * 68 + (bid >> 3);
  const int bsel = item >= 272;
  const int id = item - (bsel ? 272 : 0);
  int TI = (int)((sqrtf(4.f * (float)id + 1.f) - 1.f) * 0.5f);
  while ((TI + 1) * (TI + 2) <= id) ++TI;
  while (TI * (TI + 1) > id) --TI;
  const int tj = id - TI * (TI + 1);          // 0..2*TI+1 (128-granular key tile)

  const unsigned short* Ab = Q + (size_t)bsel * SEQ * DIM + (size_t)(TI * 256) * DIM;
  const unsigned short* Bb = K + (size_t)bsel * SEQ * DIM + (size_t)(tj * 128) * DIM;

  const int tid = threadIdx.x;
  const int w = tid >> 6, ln = tid & 63;
  const int l15 = ln & 15, quad = ln >> 4;
  const int wr = w >> 1, wc = w & 1;

  f32x4 acc[4][4] = {};

  stageA_qk(Ab, As[0], tid);
  stageB_qk(Bb, Bs[0], tid);
  stageA_qk(Ab + 32, As[1], tid);
  stageB_qk(Bb + 32, Bs[1], tid);

#pragma unroll 1
  for (int v = 0; v < 32; ++v) {
    const int p = v & 1;
    head_n3(v + 1 < 32);
    compute_qk(As[p], Bs[p], wr, wc, l15, quad, acc);
    tail_bar();
    if (v + 2 < 32) {
      stageA_qk(Ab + (v + 2) * 32, As[p], tid);
      stageB_qk(Bb + (v + 2) * 32, Bs[p], tid);
    }
  }

  const int Lt = (TI + 1) << 8;
  unsigned short* base = Sp + (size_t)bsel * PSIZE2 + (size_t)(TI * (TI + 1) / 2) * TSZ2;
#pragma unroll
  for (int fm = 0; fm < 4; ++fm)
#pragma unroll
    for (int fn = 0; fn < 4; ++fn) {
      const int mloc = wr * 64 + fm * 16 + quad * 4;
      const int col  = tj * 128 + wc * 64 + fn * 16 + l15;
      unsigned short* pp = base + (size_t)mloc * Lt + col;
#pragma unroll
      for (int r = 0; r < 4; ++r) pp[(size_t)r * Lt] = f2h(acc[fm][fn][r]);
    }
}

// ---------------- row softmax on 256-packed S (r5, proven) ------------------
__global__ __launch_bounds__(256) void sm_rows_p(unsigned short* __restrict__ Sp)
{
  const int bid = blockIdx.x;
  const int bsel = bid >> 12;
  const int r = bid & 4095;
  const int TI = r >> 8, ri = r & 255;
  const int Lt = (TI + 1) << 8;
  const int len = r + 1;
  unsigned short* row = Sp + (size_t)bsel * PSIZE2 +
                        (size_t)(TI * (TI + 1) / 2) * TSZ2 + (size_t)ri * Lt;
  const int t = threadIdx.x;
  __shared__ float red[8];

  float v[16];
#pragma unroll
  for (int it = 0; it < 2; ++it) {
    const int c = t * 8 + it * 2048;
    if (c < Lt) {
      u16x8 h = *(const u16x8*)(row + c);
#pragma unroll
      for (int i = 0; i < 8; ++i)
        v[it * 8 + i] = (c + i < len) ? h2f(h[i]) : -1e30f;
    } else {
#pragma unroll
      for (int i = 0; i < 8; ++i) v[it * 8 + i] = -1e30f;
    }
  }

  float mx = v[0];
#pragma unroll
  for (int i = 1; i < 16; ++i) mx = fmaxf(mx, v[i]);
#pragma unroll
  for (int off = 1; off < 64; off <<= 1) mx = fmaxf(mx, __shfl_xor(mx, off));
  if ((t & 63) == 0) red[t >> 6] = mx;
  __syncthreads();
  mx = fmaxf(fmaxf(red[0], red[1]), fmaxf(red[2], red[3]));

  float p[16];
  float sm = 0.f;
#pragma unroll
  for (int it = 0; it < 2; ++it) {
    const int c = t * 8 + it * 2048;
#pragma unroll
    for (int i = 0; i < 8; ++i) {
      const int k = it * 8 + i;
      p[k] = (c + i < len) ? __expf(v[k] - mx) : 0.f;
      sm += p[k];
    }
  }
#pragma unroll
  for (int off = 1; off < 64; off <<= 1) sm += __shfl_xor(sm, off);
  if ((t & 63) == 0) red[4 + (t >> 6)] = sm;
  __syncthreads();
  const float inv = 1.f / (red[4] + red[5] + red[6] + red[7]);

#pragma unroll
  for (int it = 0; it < 2; ++it) {
    const int c = t * 8 + it * 2048;
    if (c < Lt) {
      u16x8 o;
#pragma unroll
      for (int i = 0; i < 8; ++i) o[i] = f2bf(p[it * 8 + i] * inv);
      *(u16x8*)(row + c) = o;
    }
  }
}

// ============================================================================
// PV: 256m x 64n tile, BK=64, 512 thr / 8 waves (4m x 2n, wave 64x32).
// Block runs paired TI = {pr, 15-pr} -> uniform 68 K-tiles; 256 blocks, 1/CU.
// LDS 80 KB: A[2][256x64] + B[2][64x64]. 128B rows, XOR group ^ (row&7).
// ============================================================================
static __device__ __forceinline__ void stageA_pv(
    const unsigned short* __restrict__ g, int ld, unsigned short* dst, int tid)
{
  const int w = tid >> 6, ln = tid & 63;
#pragma unroll
  for (int l = 0; l < 4; ++l) {
    const int row = l * 64 + w * 8 + (ln >> 3);
    const int grp = (ln & 7) ^ (row & 7);
    __builtin_amdgcn_global_load_lds(
        (const AS1 void*)(g + (size_t)row * ld + grp * 8),
        (AS3 void*)&dst[(l * 64 + w * 8) * 64], 16, 0, 0);
  }
}

static __device__ __forceinline__ void stageB_pv(
    const unsigned short* __restrict__ g, unsigned short* dst, int tid)
{
  const int w = tid >> 6, ln = tid & 63;
  const int row = w * 8 + (ln >> 3);
  const int grp = (ln & 7) ^ (row & 7);
  __builtin_amdgcn_global_load_lds(
      (const AS1 void*)(g + (size_t)row * SEQ + grp * 8),
      (AS3 void*)&dst[(w * 8) * 64], 16, 0, 0);
}

static __device__ __forceinline__ void compute_pv(
    const unsigned short* Al, const unsigned short* Bl,
    int wr, int wc, int l15, int quad, f32x4 (&acc)[4][2])
{
#pragma unroll
  for (int ks = 0; ks < 2; ++ks) {
    bf16x8 af[4], bq[2];
#pragma unroll
    for (int i = 0; i < 4; ++i) {
      const int ar = wr * 64 + i * 16 + l15;
      af[i] = *(const bf16x8*)&Al[ar * 64 + (((ks * 4 + quad) ^ (ar & 7)) * 8)];
    }
#pragma unroll
    for (int j = 0; j < 2; ++j) {
      const int br = wc * 32 + j * 16 + l15;
      bq[j] = *(const bf16x8*)&Bl[br * 64 + (((ks * 4 + quad) ^ (br & 7)) * 8)];
    }
    __builtin_amdgcn_s_setprio(1);
#pragma unroll
    for (int i = 0; i < 4; ++i)
#pragma unroll
      for (int j = 0; j < 2; ++j)
        acc[i][j] = __builtin_amdgcn_mfma_f32_16x16x32_bf16(af[i], bq[j], acc[i][j], 0, 0, 0);
    __builtin_amdgcn_s_setprio(0);
  }
}

__global__ __launch_bounds__(512, 2) void pv_gemm6(
    const unsigned short* __restrict__ Sp,
    const unsigned short* __restrict__ Vt,
    float* __restrict__ Ob)
{
  __shared__ unsigned short As[2][256 * 64];
  __shared__ unsigned short Bs[2][64 * 64];

  const int bid = blockIdx.x;                 // 256
  const int xcd = bid & 7, idx = bid >> 3;    // idx 0..31
  const int nt = xcd * 2 + (idx >> 4);        // 0..15 (64-wide dim slice)
  const int b  = (idx >> 3) & 1;
  const int pr = idx & 7;

  const unsigned short* Sbase = Sp + (size_t)b * PSIZE2;
  const unsigned short* Vb = Vt + (size_t)b * ((size_t)DIM * SEQ) +
                             (size_t)(nt * 64) * SEQ;
  float* Outb = Ob + (size_t)b * ((size_t)SEQ * DIM);

  const int tid = threadIdx.x;
  const int w = tid >> 6, ln = tid & 63;
  const int l15 = ln & 15, quad = ln >> 4;
  const int wr = w >> 1, wc = w & 1;

#pragma unroll 1
  for (int gsel = 0; gsel < 2; ++gsel) {
    const int TI = gsel ? (15 - pr) : pr;
    const int Lt = (TI + 1) << 8;
    const int ntk = (TI + 1) * 4;             // BK64 tiles
    const unsigned short* Ab = Sbase + (size_t)(TI * (TI + 1) / 2) * TSZ2;

    f32x4 acc[4][2] = {};

    stageA_pv(Ab, Lt, As[0], tid);
    stageB_pv(Vb, Bs[0], tid);
    stageA_pv(Ab + 64, Lt, As[1], tid);
    stageB_pv(Vb + 64, Bs[1], tid);

#pragma unroll 1
    for (int v = 0; v < ntk; ++v) {
      const int p = v & 1;
      head_n5(v + 1 < ntk);
      compute_pv(As[p], Bs[p], wr, wc, l15, quad, acc);
      tail_bar();
      if (v + 2 < ntk) {
        stageA_pv(Ab + (v + 2) * 64, Lt, As[p], tid);
        stageB_pv(Vb + (v + 2) * 64, Bs[p], tid);
      }
    }

#pragma unroll
    for (int fm = 0; fm < 4; ++fm)
#pragma unroll
      for (int fn = 0; fn < 2; ++fn) {
        const int m = TI * 256 + wr * 64 + fm * 16 + quad * 4;
        const int e = nt * 64 + wc * 32 + fn * 16 + l15;
        float* pp = Outb + (size_t)m * DIM + e;
#pragma unroll
        for (int r = 0; r < 4; ++r) pp[(size_t)r * DIM] = acc[fm][fn][r];
      }
  }
}

extern "C" void kernel_launch(void* const* d_in, const int* in_sizes, int n_in,
                              void* d_out, int out_size, void* d_ws, size_t ws_size,
                              hipStream_t stream) {
  const float* x  = (const float*)d_in[0];
  const float* Wq = (const float*)d_in[1];
  const float* Wk = (const float*)d_in[2];
  const float* Wv = (const float*)d_in[3];
  float* out = (float*)d_out;

  // ws layout (134.25 MB):
  //   [0,38MB):    xb (bf16 x, 32MB) + Wb (bf16 weights, 6MB)
  //                -> after qkv: 256-packed causal S, 2 batches (2 x 17.8MB)
  //   [38,70MB):   Q bf16   [70,102MB): K bf16   [102,134MB): Vt bf16
  char* wsb = (char*)d_ws;
  unsigned short* xb = (unsigned short*)wsb;
  unsigned short* Wb = (unsigned short*)(wsb + (32u << 20));
  unsigned short* Qb = (unsigned short*)(wsb + (38u << 20));
  unsigned short* Sp = xb;

  conv_bf16<<<8192, 256, 0, stream>>>(x, xb, 2097152, 1.0f);
  conv_w3<<<1536, 256, 0, stream>>>(Wq, Wk, Wv, Wb);

  qkv_gemm5<<<256, 1024, 0, stream>>>(xb, Wb, Qb);

  const size_t n = (size_t)MTOT * DIM;
  for (int p = 0; p < 2; ++p) {
    const unsigned short* Qp  = Qb + (size_t)p * 2 * SEQ * DIM;
    const unsigned short* Kp  = Qb + n + (size_t)p * 2 * SEQ * DIM;
    const unsigned short* Vtp = Qb + 2 * n + (size_t)p * 2 * DIM * SEQ;
    float* Op = out + (size_t)p * 2 * SEQ * DIM;

    qk_gemm6<<<544, 512, 0, stream>>>(Qp, Kp, Sp);
    sm_rows_p<<<8192, 256, 0, stream>>>(Sp);
    pv_gemm6<<<256, 512, 0, stream>>>(Sp, Vtp, Op);
  }
}